// Round 4
// baseline (446.443 us; speedup 1.0000x reference)
//
#include <hip/hip_runtime.h>
#include <math.h>

#define COUT 192
#define NF 12

typedef __bf16 bf16_8 __attribute__((ext_vector_type(8)));
typedef float  f32x4  __attribute__((ext_vector_type(4)));

#define ACC_SCALE 65536.0f
#define ACC_INV   1.52587890625e-5f

__device__ __forceinline__ float fast_tanh125(float d) {
    // tanh(12.5*d) = 1 - 2/(exp2(36.0674*d)+1)
    float e = __builtin_amdgcn_exp2f(d * 36.06737602222409f);
    return 1.0f - 2.0f * __builtin_amdgcn_rcpf(e + 1.0f);
}

__device__ __forceinline__ void gl_lds16(const void* gptr, void* lptr) {
    auto g = (const __attribute__((address_space(1))) unsigned int*)gptr;
    auto l = (__attribute__((address_space(3))) unsigned int*)lptr;
    __builtin_amdgcn_global_load_lds(g, l, 16, 0, 0);
}

// ---- weight prep: Bp[(cc*NF+nf)*64 + lane][8] bf16, cc=c*2+t, k=(lane>>4)*8+e, n=nf*16+(lane&15)
template<int CIN>
__global__ void prep_w(const float* __restrict__ m_w, const float* __restrict__ w_w,
                       __bf16* __restrict__ Bp) {
    int idx = blockIdx.x * 256 + threadIdx.x;
    const int total = CIN * 2 * NF * 64;
    if (idx >= total) return;
    int lane = idx & 63;
    int nf = (idx >> 6) % NF;
    int cc = idx / (NF * 64);
    int t = cc & 1, c = cc >> 1;
    int n = nf * 16 + (lane & 15);
    int k0 = (lane >> 4) * 8;
    bf16_8 v;
    #pragma unroll
    for (int e = 0; e < 8; ++e) {
        int k = k0 + e;
        float val = 0.f;
        if (k < 25) {
            val = (t == 0) ? m_w[((size_t)n * CIN + c) * 25 + k]
                           : -2.0f * w_w[((size_t)n * CIN + c) * 25 + k];
        }
        v[e] = (__bf16)val;
    }
    *(bf16_8*)(Bp + (size_t)idx * 8) = v;
}

// ---- Layer 1: INRF(3->192, 32x32) + fused 2x2 maxpool -> x00 [64,192,16,16]  (verified)
__global__ __launch_bounds__(256, 3) void inrf1_mfma(
    const float* __restrict__ x, const __bf16* __restrict__ Bp,
    const float* __restrict__ bias, float* __restrict__ x00)
{
    __shared__ float win[3][6][36];
    __shared__ float hp[192][33];

    const int b  = blockIdx.x >> 4;
    const int h0 = (blockIdx.x & 15) * 2;
    const int tid = threadIdx.x;
    const int wv = tid >> 6, lane = tid & 63;
    const int hl = wv >> 1, half = wv & 1;
    const int mcol = lane & 15, q = lane >> 4;
    const int wpos = half * 16 + mcol;

    for (int i = tid; i < 3 * 6 * 36; i += 256) {
        int c = i / 216, r = (i / 36) % 6, cc = i % 36;
        int gr = h0 + r - 2, gc = cc - 2;
        float v = 0.f;
        if (gr >= 0 && gr < 32 && gc >= 0 && gc < 32)
            v = x[((size_t)(b * 3 + c) * 32 + gr) * 32 + gc];
        win[c][r][cc] = v;
    }
    __syncthreads();

    int offs[8]; bool kok[8];
    #pragma unroll
    for (int e = 0; e < 8; ++e) {
        int k = q * 8 + e;
        kok[e] = (k < 25);
        int kk = kok[e] ? k : 0;
        offs[e] = (hl + kk / 5) * 36 + wpos + (kk % 5);
    }
    const int cen_off = (hl + 2) * 36 + wpos + 2;

    f32x4 acc[NF];
    #pragma unroll
    for (int j = 0; j < NF; ++j) acc[j] = (f32x4){0.f, 0.f, 0.f, 0.f};

    const float* winf = &win[0][0][0];
    for (int c = 0; c < 3; ++c) {
        const float* wf = winf + c * 216;
        float cen = wf[cen_off];
        float vv[8];
        bf16_8 av, as_;
        #pragma unroll
        for (int e = 0; e < 8; ++e) {
            float v = wf[offs[e]];
            vv[e] = kok[e] ? v : 0.f;
            av[e] = (__bf16)vv[e];
        }
        #pragma unroll
        for (int e = 0; e < 8; ++e) {
            float s = fast_tanh125(vv[e] - cen);
            as_[e] = (__bf16)(kok[e] ? s : 0.f);
        }
        const bf16_8* b0 = (const bf16_8*)Bp + ((size_t)(c * 2 + 0) * NF) * 64 + lane;
        const bf16_8* b1 = b0 + NF * 64;
        #pragma unroll
        for (int j = 0; j < NF; ++j)
            acc[j] = __builtin_amdgcn_mfma_f32_16x16x32_bf16(av, b0[j * 64], acc[j], 0, 0, 0);
        #pragma unroll
        for (int j = 0; j < NF; ++j)
            acc[j] = __builtin_amdgcn_mfma_f32_16x16x32_bf16(as_, b1[j * 64], acc[j], 0, 0, 0);
    }

    #pragma unroll
    for (int j = 0; j < NF; ++j) {
        int n = j * 16 + mcol;
        hp[n][hl * 16 + half * 8 + q * 2 + 0] = fmaxf(acc[j][0], acc[j][1]);
        hp[n][hl * 16 + half * 8 + q * 2 + 1] = fmaxf(acc[j][2], acc[j][3]);
    }
    __syncthreads();

    const int hpout = h0 >> 1;
    for (int i = tid; i < 192 * 16; i += 256) {
        int n = i >> 4, wp = i & 15;
        float v = fmaxf(hp[n][wp], hp[n][16 + wp]) + bias[n];
        x00[((size_t)(b * COUT + n) * 16 + hpout) * 16 + wp] = v;
    }
}

// ---- zero the int32 accumulator
__global__ void zeroacc(int* __restrict__ xacc) {
    int idx = blockIdx.x * 256 + threadIdx.x;
    if (idx < 64 * COUT * 256) xacc[idx] = 0;
}

// ---- Layer 2: INRF(192->192, 16x16). 4 waves; wave owns 4 m-tiles x all 24 N-frags.
// KSPLIT=8 over input channels; DETERMINISTIC int32 fixed-point atomics into xacc.
__global__ __launch_bounds__(256, 2) void inrf2_mfma(
    const float* __restrict__ xin, const __bf16* __restrict__ Bp,
    int* __restrict__ xacc)
{
    constexpr int CPS = 24;            // 192 / KSPLIT(8)
    __shared__ __align__(16) __bf16 Bs[2][24 * 64 * 8];   // 2 x 24 KiB
    __shared__ float win[2][20 * 21];

    const int b  = blockIdx.x >> 3;
    const int ks = blockIdx.x & 7;
    const int c0 = ks * CPS;
    const int tid = threadIdx.x;
    const int wv = tid >> 6, lane = tid & 63;
    const int wp = lane & 15, q = lane >> 4;

    int offs[8]; bool kok[8];
    #pragma unroll
    for (int e = 0; e < 8; ++e) {
        int k = q * 8 + e;
        kok[e] = (k < 25);
        int kk = kok[e] ? k : 0;
        offs[e] = (kk / 5) * 21 + (kk % 5);
    }

    const int j0 = tid, j1 = tid + 256;
    const int r0_ = j0 / 20, c0_ = j0 % 20;
    const int r1_ = j1 / 20, c1_ = j1 % 20;
    const bool ok0 = (r0_ >= 2 && r0_ < 18 && c0_ >= 2 && c0_ < 18);
    const bool ok1 = (j1 < 400) && (r1_ >= 2 && r1_ < 18 && c1_ >= 2 && c1_ < 18);
    const float* xb = xin + (size_t)b * COUT * 256;

    f32x4 acc[4][12];
    #pragma unroll
    for (int m = 0; m < 4; ++m)
        #pragma unroll
        for (int j = 0; j < 12; ++j) acc[m][j] = (f32x4){0.f, 0.f, 0.f, 0.f};

    {   // prologue: stage c0 into buffer 0
        float v0 = 0.f, v1 = 0.f;
        if (ok0) v0 = xb[(size_t)c0 * 256 + (r0_ - 2) * 16 + (c0_ - 2)];
        if (ok1) v1 = xb[(size_t)c0 * 256 + (r1_ - 2) * 16 + (c1_ - 2)];
        const __bf16* gB = Bp + (size_t)c0 * 2 * NF * 64 * 8 + wv * 3072 + lane * 8;
        #pragma unroll
        for (int i = 0; i < 6; ++i)
            gl_lds16(gB + i * 512, &Bs[0][wv * 3072 + i * 512]);
        win[0][r0_ * 21 + c0_] = v0;
        if (j1 < 400) win[0][r1_ * 21 + c1_] = v1;
    }
    __syncthreads();

    int cur = 0;
    for (int r = 0; r < CPS; ++r) {
        const int nxt = cur ^ 1;
        if (r + 1 < CPS) {
            const int c = c0 + r + 1;
            float v0 = 0.f, v1 = 0.f;
            if (ok0) v0 = xb[(size_t)c * 256 + (r0_ - 2) * 16 + (c0_ - 2)];
            if (ok1) v1 = xb[(size_t)c * 256 + (r1_ - 2) * 16 + (c1_ - 2)];
            const __bf16* gB = Bp + (size_t)c * 2 * NF * 64 * 8 + wv * 3072 + lane * 8;
            #pragma unroll
            for (int i = 0; i < 6; ++i)
                gl_lds16(gB + i * 512, &Bs[nxt][wv * 3072 + i * 512]);
            win[nxt][r0_ * 21 + c0_] = v0;
            if (j1 < 400) win[nxt][r1_ * 21 + c1_] = v1;
        }

        const float* wc = win[cur];
        bf16_8 av[4], as_[4];
        #pragma unroll
        for (int m = 0; m < 4; ++m) {
            const int base = (wv * 4 + m) * 21 + wp;
            float cen = wc[base + 44];
            #pragma unroll
            for (int e = 0; e < 8; ++e) {
                float v = wc[base + offs[e]];
                v = kok[e] ? v : 0.f;
                av[m][e] = (__bf16)v;
                float s = fast_tanh125(v - cen);
                as_[m][e] = (__bf16)(kok[e] ? s : 0.f);
            }
        }

        const bf16_8* Bf = (const bf16_8*)(Bs[cur]) + lane;
        #pragma unroll
        for (int j = 0; j < 12; ++j) {
            bf16_8 fm = Bf[j * 64];
            bf16_8 fs = Bf[(12 + j) * 64];
            #pragma unroll
            for (int m = 0; m < 4; ++m) {
                acc[m][j] = __builtin_amdgcn_mfma_f32_16x16x32_bf16(av[m],  fm, acc[m][j], 0, 0, 0);
                acc[m][j] = __builtin_amdgcn_mfma_f32_16x16x32_bf16(as_[m], fs, acc[m][j], 0, 0, 0);
            }
        }
        __syncthreads();
        cur = nxt;
    }

    // epilogue: deterministic fixed-point atomic accumulate.
    #pragma unroll
    for (int j = 0; j < 12; ++j) {
        int n = j * 16 + wp;
        int* outp = xacc + ((size_t)b * COUT + n) * 256 + q * 4;
        #pragma unroll
        for (int m = 0; m < 4; ++m) {
            int h = wv * 4 + m;
            #pragma unroll
            for (int e = 0; e < 4; ++e) {
                int qv = __float2int_rn(acc[m][j][e] * ACC_SCALE);
                atomicAdd(outp + h * 16 + e, qv);
            }
        }
    }
}

// ---- x01 = xacc * 2^-16 + bias
__global__ void x01fin(const int* __restrict__ xacc, const float* __restrict__ bias,
                       float* __restrict__ x01) {
    int idx = blockIdx.x * 256 + threadIdx.x;
    if (idx >= 64 * COUT * 256) return;
    x01[idx] = (float)xacc[idx] * ACC_INV + bias[(idx >> 8) % COUT];
}

// ---- finish2: x01 -> maxpool(8x8) -> region-sums W, tanh-sums T -> An (bf16 A-frags, /64)
__global__ __launch_bounds__(512) void finish2(
    const float* __restrict__ x01, __bf16* __restrict__ An)
{
    __shared__ float xbuf[8][256];
    const int b  = blockIdx.x / 24;
    const int cg = blockIdx.x % 24;
    const int tid = threadIdx.x;
    const int wv = tid >> 6, lane = tid & 63;
    const int ch = cg * 8 + wv;

    const float* p = x01 + ((size_t)b * COUT + ch) * 256;
    #pragma unroll
    for (int i = 0; i < 4; ++i) xbuf[wv][lane + 64 * i] = p[lane + 64 * i];
    __syncthreads();

    const int ph = lane >> 3, pw = lane & 7;
    const int i0 = ph * 32 + pw * 2;
    float x8 = fmaxf(fmaxf(xbuf[wv][i0], xbuf[wv][i0 + 1]),
                     fmaxf(xbuf[wv][i0 + 16], xbuf[wv][i0 + 17]));

    float myT = 0.f, myW = 0.f;
    #pragma unroll
    for (int k = 0; k < 25; ++k) {
        const int dy = k / 5 - 2, dx = k % 5 - 2;
        const bool valid = (ph + dy >= 0) && (ph + dy < 8) && (pw + dx >= 0) && (pw + dx < 8);
        float nb = __shfl(x8, (lane + dy * 8 + dx) & 63);
        nb = valid ? nb : 0.f;
        float tS = fast_tanh125(nb - x8);
        float wS = nb;
        #pragma unroll
        for (int off = 1; off < 64; off <<= 1) {
            tS += __shfl_xor(tS, off);
            wS += __shfl_xor(wS, off);
        }
        if (lane == k) { myT = tS; myW = wS; }
    }

    const int mt = b >> 4;
    if (lane < 25) {
        const int k = lane;
        const int la = (k >> 3) * 16 + (b & 15);
        const int e = k & 7;
        const int ccW = ch * 2, ccT = ch * 2 + 1;
        An[((size_t)(ccW * 4 + mt) * 64 + la) * 8 + e] = (__bf16)(myW * 0.015625f);
        An[((size_t)(ccT * 4 + mt) * 64 + la) * 8 + e] = (__bf16)(myT * 0.015625f);
    } else if (lane < 32) {
        // zero-fill padding slots (k=25..31) for determinism (ws is poisoned, not zeroed)
        const int la = 3 * 16 + (b & 15);
        const int e = lane & 7;
        const int ccW = ch * 2, ccT = ch * 2 + 1;
        An[((size_t)(ccW * 4 + mt) * 64 + la) * 8 + e] = (__bf16)0.f;
        An[((size_t)(ccT * 4 + mt) * 64 + la) * 8 + e] = (__bf16)0.f;
    }
}

// ---- tiny GEMM: feat-partials [96][192][64] = An[64 x 12288] * Bp3[12288 x 192]
__global__ __launch_bounds__(512) void gemm3p(
    const __bf16* __restrict__ An, const __bf16* __restrict__ Bp,
    float* __restrict__ part)
{
    const int ks = blockIdx.x;          // 96 blocks, 4 cc each
    const int tid = threadIdx.x;
    const int wv = tid >> 6, lane = tid & 63;
    const int mt = wv & 3, nh = wv >> 2;

    f32x4 acc[6];
    #pragma unroll
    for (int j = 0; j < 6; ++j) acc[j] = (f32x4){0.f, 0.f, 0.f, 0.f};

    for (int i = 0; i < 4; ++i) {
        const int cc = ks * 4 + i;
        bf16_8 a = *(const bf16_8*)(An + ((size_t)(cc * 4 + mt) * 64 + lane) * 8);
        #pragma unroll
        for (int j = 0; j < 6; ++j) {
            bf16_8 bw = *(const bf16_8*)(Bp + ((size_t)(cc * NF + nh * 6 + j) * 64 + lane) * 8);
            acc[j] = __builtin_amdgcn_mfma_f32_16x16x32_bf16(a, bw, acc[j], 0, 0, 0);
        }
    }
    #pragma unroll
    for (int j = 0; j < 6; ++j) {
        int n = (nh * 6 + j) * 16 + (lane & 15);
        *(f32x4*)(part + ((size_t)ks * COUT + n) * 64 + mt * 16 + (lane >> 4) * 4) = acc[j];
    }
}

// ---- logits: feat = sum of 96 partials + m3_b; logits = feat @ fc_w^T + fc_b
__global__ __launch_bounds__(256) void logitsk(
    const float* __restrict__ part, const float* __restrict__ m3_b,
    const float* __restrict__ fc_w, const float* __restrict__ fc_b,
    float* __restrict__ logits)
{
    __shared__ float feat[COUT];
    const int b = blockIdx.x;
    const int t = threadIdx.x;
    if (t < COUT) {
        float s = 0.f;
        for (int ks = 0; ks < 96; ++ks) s += part[((size_t)ks * COUT + t) * 64 + b];
        feat[t] = s + m3_b[t];
    }
    __syncthreads();
    if (t < 10) {
        float s = fc_b[t];
        #pragma unroll 8
        for (int c = 0; c < COUT; ++c) s = fmaf(fc_w[t * COUT + c], feat[c], s);
        logits[(size_t)b * 10 + t] = s;
    }
}

extern "C" void kernel_launch(void* const* d_in, const int* in_sizes, int n_in,
                              void* d_out, int out_size, void* d_ws, size_t ws_size,
                              hipStream_t stream) {
    const float* x    = (const float*)d_in[0];
    const float* m1_w = (const float*)d_in[1];
    const float* m1_b = (const float*)d_in[2];
    const float* w1_w = (const float*)d_in[3];
    const float* m2_w = (const float*)d_in[4];
    const float* m2_b = (const float*)d_in[5];
    const float* w2_w = (const float*)d_in[6];
    const float* m3_w = (const float*)d_in[7];
    const float* m3_b = (const float*)d_in[8];
    const float* w3_w = (const float*)d_in[9];
    const float* fc_w = (const float*)d_in[10];
    const float* fc_b = (const float*)d_in[11];

    float* out = (float*)d_out;
    float* ws  = (float*)d_ws;

    // d_out: [logits(640) | x00(3145728) | x01(3145728)]
    float* logits = out;
    float* x00 = out + 640;
    float* x01 = out + 640 + 3145728;

    // ws (float units):
    __bf16* Bp1 = (__bf16*)(ws);                 //    36,864 bf16 (18,432 f)
    __bf16* Bp2 = (__bf16*)(ws + 18432);         // 2,359,296 bf16 (1,179,648 f)
    __bf16* Bp3 = (__bf16*)(ws + 1198080);       // 2,359,296 bf16 (1,179,648 f)
    __bf16* An  = (__bf16*)(ws + 2377728);       //   786,432 bf16 (393,216 f)
    int*   xacc = (int*)(ws + 2770944);          // 3,145,728 i32  (also aliased by part)
    float* part = ws + 2770944;                  // 1,179,648 f32  (reuse: written after xacc's last read)

    prep_w<3>  <<<(3   * 2 * NF * 64 + 255) / 256, 256, 0, stream>>>(m1_w, w1_w, Bp1);
    prep_w<192><<<(192 * 2 * NF * 64 + 255) / 256, 256, 0, stream>>>(m2_w, w2_w, Bp2);
    prep_w<192><<<(192 * 2 * NF * 64 + 255) / 256, 256, 0, stream>>>(m3_w, w3_w, Bp3);
    zeroacc<<<12288, 256, 0, stream>>>(xacc);

    inrf1_mfma<<<64 * 16, 256, 0, stream>>>(x, Bp1, m1_b, x00);
    inrf2_mfma<<<64 * 8, 256, 0, stream>>>(x00, Bp2, xacc);
    x01fin<<<12288, 256, 0, stream>>>(xacc, m2_b, x01);
    finish2<<<64 * 24, 512, 0, stream>>>(x01, An);
    gemm3p<<<96, 512, 0, stream>>>(An, Bp3, part);
    logitsk<<<64, 256, 0, stream>>>(part, m3_b, fc_w, fc_b, logits);
}

// Round 6
// 222.533 us; speedup vs baseline: 2.0062x; 2.0062x over previous
//
#include <hip/hip_runtime.h>
#include <math.h>

#define COUT 192
#define NF 12

typedef __bf16 bf16_8 __attribute__((ext_vector_type(8)));
typedef float  f32x4  __attribute__((ext_vector_type(4)));

__device__ __forceinline__ float fast_tanh125(float d) {
    // tanh(12.5*d) = 1 - 2/(exp2(36.0674*d)+1)
    float e = __builtin_amdgcn_exp2f(d * 36.06737602222409f);
    return 1.0f - 2.0f * __builtin_amdgcn_rcpf(e + 1.0f);
}

__device__ __forceinline__ void gl_lds16(const void* gptr, void* lptr) {
    auto g = (const __attribute__((address_space(1))) unsigned int*)gptr;
    auto l = (__attribute__((address_space(3))) unsigned int*)lptr;
    __builtin_amdgcn_global_load_lds(g, l, 16, 0, 0);
}

// ---- weight prep: Bp[(cc*NF+nf)*64 + lane][8] bf16, cc=c*2+t, k=(lane>>4)*8+e, n=nf*16+(lane&15)
template<int CIN>
__global__ void prep_w(const float* __restrict__ m_w, const float* __restrict__ w_w,
                       __bf16* __restrict__ Bp) {
    int idx = blockIdx.x * 256 + threadIdx.x;
    const int total = CIN * 2 * NF * 64;
    if (idx >= total) return;
    int lane = idx & 63;
    int nf = (idx >> 6) % NF;
    int cc = idx / (NF * 64);
    int t = cc & 1, c = cc >> 1;
    int n = nf * 16 + (lane & 15);
    int k0 = (lane >> 4) * 8;
    bf16_8 v;
    #pragma unroll
    for (int e = 0; e < 8; ++e) {
        int k = k0 + e;
        float val = 0.f;
        if (k < 25) {
            val = (t == 0) ? m_w[((size_t)n * CIN + c) * 25 + k]
                           : -2.0f * w_w[((size_t)n * CIN + c) * 25 + k];
        }
        v[e] = (__bf16)val;
    }
    *(bf16_8*)(Bp + (size_t)idx * 8) = v;
}

// ---- Layer 1: INRF(3->192, 32x32) + fused 2x2 maxpool -> x00 [64,192,16,16]  (verified)
__global__ __launch_bounds__(256, 3) void inrf1_mfma(
    const float* __restrict__ x, const __bf16* __restrict__ Bp,
    const float* __restrict__ bias, float* __restrict__ x00)
{
    __shared__ float win[3][6][36];
    __shared__ float hp[192][33];

    const int b  = blockIdx.x >> 4;
    const int h0 = (blockIdx.x & 15) * 2;
    const int tid = threadIdx.x;
    const int wv = tid >> 6, lane = tid & 63;
    const int hl = wv >> 1, half = wv & 1;
    const int mcol = lane & 15, q = lane >> 4;
    const int wpos = half * 16 + mcol;

    for (int i = tid; i < 3 * 6 * 36; i += 256) {
        int c = i / 216, r = (i / 36) % 6, cc = i % 36;
        int gr = h0 + r - 2, gc = cc - 2;
        float v = 0.f;
        if (gr >= 0 && gr < 32 && gc >= 0 && gc < 32)
            v = x[((size_t)(b * 3 + c) * 32 + gr) * 32 + gc];
        win[c][r][cc] = v;
    }
    __syncthreads();

    int offs[8];
    #pragma unroll
    for (int e = 0; e < 8; ++e) {
        int k = q * 8 + e;
        int kk = (k < 25) ? k : 0;      // pad elems hit B-weight zeros; value don't-care
        offs[e] = (hl + kk / 5) * 36 + wpos + (kk % 5);
    }
    const int cen_off = (hl + 2) * 36 + wpos + 2;

    f32x4 acc[NF];
    #pragma unroll
    for (int j = 0; j < NF; ++j) acc[j] = (f32x4){0.f, 0.f, 0.f, 0.f};

    const float* winf = &win[0][0][0];
    for (int c = 0; c < 3; ++c) {
        const float* wf = winf + c * 216;
        float cen = wf[cen_off];
        bf16_8 av, as_;
        #pragma unroll
        for (int e = 0; e < 8; ++e) {
            float v = wf[offs[e]];
            av[e] = (__bf16)v;
            as_[e] = (__bf16)fast_tanh125(v - cen);
        }
        const bf16_8* b0 = (const bf16_8*)Bp + ((size_t)(c * 2 + 0) * NF) * 64 + lane;
        const bf16_8* b1 = b0 + NF * 64;
        #pragma unroll
        for (int j = 0; j < NF; ++j)
            acc[j] = __builtin_amdgcn_mfma_f32_16x16x32_bf16(av, b0[j * 64], acc[j], 0, 0, 0);
        #pragma unroll
        for (int j = 0; j < NF; ++j)
            acc[j] = __builtin_amdgcn_mfma_f32_16x16x32_bf16(as_, b1[j * 64], acc[j], 0, 0, 0);
    }

    #pragma unroll
    for (int j = 0; j < NF; ++j) {
        int n = j * 16 + mcol;
        hp[n][hl * 16 + half * 8 + q * 2 + 0] = fmaxf(acc[j][0], acc[j][1]);
        hp[n][hl * 16 + half * 8 + q * 2 + 1] = fmaxf(acc[j][2], acc[j][3]);
    }
    __syncthreads();

    const int hpout = h0 >> 1;
    for (int i = tid; i < 192 * 16; i += 256) {
        int n = i >> 4, wp = i & 15;
        float v = fmaxf(hp[n][wp], hp[n][16 + wp]) + bias[n];
        x00[((size_t)(b * COUT + n) * 16 + hpout) * 16 + wp] = v;
    }
}

// ---- Layer 2: INRF(192->192, 16x16), KSPLIT=4 (48 ch/block), NO atomics.
// Grid 256 = 64 img x 4 ks. 4 waves; wave owns 4 m-tiles x all 24 N-frags (m_rep=4).
// Triple-buffered LDS, depth-2 prefetch, rotated A-build, deferred window ds_write.
// ks=0 -> x01 region of d_out; ks=1..3 -> ws partials (fixed-order reduce in finish2).
__global__ __launch_bounds__(256, 1) void inrf2_mfma(
    const float* __restrict__ xin, const __bf16* __restrict__ Bp,
    float* __restrict__ out0, float* __restrict__ part)
{
    constexpr int CPS = 48;
    __shared__ __align__(16) __bf16 Bs[3][24 * 64 * 8];   // 3 x 24 KiB
    __shared__ float win[3][420];                         // [20 rows][stride 21]

    const int b  = blockIdx.x >> 2;
    const int ks = blockIdx.x & 3;
    const int c0 = ks * CPS;
    const int tid = threadIdx.x;
    const int wv = tid >> 6, lane = tid & 63;
    const int wp = lane & 15, q = lane >> 4;

    int offs[8];
    #pragma unroll
    for (int e = 0; e < 8; ++e) {
        int k = q * 8 + e;
        int kk = (k < 25) ? k : 0;      // pad elems hit B-weight zeros; value don't-care
        offs[e] = (kk / 5) * 21 + (kk % 5);
    }

    const int j0 = tid, j1 = tid + 256;
    const int r0_ = j0 / 20, c0_ = j0 % 20;
    const int r1_ = j1 / 20, c1_ = j1 % 20;
    const int w0i = r0_ * 21 + c0_;     // stride-21 LDS slot (MUST match read stride!)
    const int w1i = r1_ * 21 + c1_;
    const bool in1 = j1 < 400;
    const bool ok0 = (r0_ >= 2 && r0_ < 18 && c0_ >= 2 && c0_ < 18);
    const bool ok1 = in1 && (r1_ >= 2 && r1_ < 18 && c1_ >= 2 && c1_ < 18);
    const float* xb = xin + (size_t)b * COUT * 256;

    f32x4 acc[4][12];
    #pragma unroll
    for (int m = 0; m < 4; ++m)
        #pragma unroll
        for (int j = 0; j < 12; ++j) acc[m][j] = (f32x4){0.f, 0.f, 0.f, 0.f};

#define BUILD_A(SLOT, AV, AS)                                              \
    {                                                                      \
        const float* wc = win[(SLOT)];                                     \
        _Pragma("unroll")                                                  \
        for (int m = 0; m < 4; ++m) {                                      \
            const int base = (wv * 4 + m) * 21 + wp;                       \
            float cen = wc[base + 44];                                     \
            _Pragma("unroll")                                              \
            for (int e = 0; e < 8; ++e) {                                  \
                float v = wc[base + offs[e]];                              \
                (AV)[m][e] = (__bf16)v;                                    \
                (AS)[m][e] = (__bf16)fast_tanh125(v - cen);                \
            }                                                              \
        }                                                                  \
    }

    // ---- prologue: stage c0+0 -> slot0, c0+1 -> slot1
    #pragma unroll
    for (int rr = 0; rr < 2; ++rr) {
        const int c = c0 + rr;
        float v0 = 0.f, v1 = 0.f;
        if (ok0) v0 = xb[(size_t)c * 256 + (r0_ - 2) * 16 + (c0_ - 2)];
        if (ok1) v1 = xb[(size_t)c * 256 + (r1_ - 2) * 16 + (c1_ - 2)];
        const __bf16* gB = Bp + (size_t)c * 2 * NF * 64 * 8 + wv * 3072 + lane * 8;
        #pragma unroll
        for (int i = 0; i < 6; ++i)
            gl_lds16(gB + i * 512, &Bs[rr][wv * 3072 + i * 512]);
        win[rr][w0i] = v0;
        if (in1) win[rr][w1i] = v1;
    }
    __syncthreads();

    bf16_8 av[4], as_[4];
    BUILD_A(0, av, as_);

    #pragma unroll 3
    for (int r = 0; r < CPS; ++r) {
        const int sl_cur = r % 3;
        const int sl_n1  = (r + 1) % 3;
        const int sl_n2  = (r + 2) % 3;
        const bool do2 = (r + 2) < CPS;
        const bool do1 = (r + 1) < CPS;

        // (1) issue next+2 window loads (regs) and B gl_lds
        float v0 = 0.f, v1 = 0.f;
        if (do2) {
            const int c = c0 + r + 2;
            if (ok0) v0 = xb[(size_t)c * 256 + (r0_ - 2) * 16 + (c0_ - 2)];
            if (ok1) v1 = xb[(size_t)c * 256 + (r1_ - 2) * 16 + (c1_ - 2)];
            const __bf16* gB = Bp + (size_t)c * 2 * NF * 64 * 8 + wv * 3072 + lane * 8;
            #pragma unroll
            for (int i = 0; i < 6; ++i)
                gl_lds16(gB + i * 512, &Bs[sl_n2][wv * 3072 + i * 512]);
        }

        // (2) build A for next c (interleaves with MFMA issue below)
        bf16_8 avN[4], asN[4];
        if (do1) BUILD_A(sl_n1, avN, asN);

        // (3) MFMA for current c: 24 B-frag reads, each feeding 4 MFMAs
        const bf16_8* Bf = (const bf16_8*)(Bs[sl_cur]) + lane;
        #pragma unroll
        for (int j = 0; j < 12; ++j) {
            bf16_8 fm = Bf[j * 64];
            bf16_8 fs = Bf[(12 + j) * 64];
            #pragma unroll
            for (int m = 0; m < 4; ++m) {
                acc[m][j] = __builtin_amdgcn_mfma_f32_16x16x32_bf16(av[m],  fm, acc[m][j], 0, 0, 0);
                acc[m][j] = __builtin_amdgcn_mfma_f32_16x16x32_bf16(as_[m], fs, acc[m][j], 0, 0, 0);
            }
        }

        // (4) deferred window ds_write (vmcnt wait lands here, late)
        if (do2) {
            win[sl_n2][w0i] = v0;
            if (in1) win[sl_n2][w1i] = v1;
        }

        // (5) rotate A frags
        if (do1) {
            #pragma unroll
            for (int m = 0; m < 4; ++m) { av[m] = avN[m]; as_[m] = asN[m]; }
        }
        __syncthreads();
    }
#undef BUILD_A

    // ---- epilogue: plain coalesced f32x4 stores
    float* outp = (ks == 0) ? out0 : (part + (size_t)(ks - 1) * 3145728);
    #pragma unroll
    for (int j = 0; j < 12; ++j) {
        int n = j * 16 + wp;
        #pragma unroll
        for (int m = 0; m < 4; ++m) {
            int h = wv * 4 + m;
            *(f32x4*)&outp[((size_t)(b * COUT + n)) * 256 + h * 16 + q * 4] = acc[m][j];
        }
    }
}

// ---- finish2: fixed-order partial reduce (+bias) -> x01 write; then maxpool(8x8)
// -> region-sums W, tanh-sums T -> An (bf16 A-frags, /64)
__global__ __launch_bounds__(512) void finish2(
    float* __restrict__ x01, const float* __restrict__ part,
    const float* __restrict__ bias, __bf16* __restrict__ An)
{
    __shared__ float xbuf[8][256];
    const int b  = blockIdx.x / 24;
    const int cg = blockIdx.x % 24;
    const int tid = threadIdx.x;
    const int wv = tid >> 6, lane = tid & 63;
    const int ch = cg * 8 + wv;

    float* p0 = x01 + ((size_t)b * COUT + ch) * 256;
    const float* pp = part + ((size_t)b * COUT + ch) * 256;
    const float bv = bias[ch];
    #pragma unroll
    for (int i = 0; i < 4; ++i) {
        int idx = lane + 64 * i;
        float s = ((p0[idx] + pp[idx]) + pp[idx + 3145728]) + pp[idx + 2 * 3145728] + bv;
        xbuf[wv][idx] = s;
        p0[idx] = s;
    }
    __syncthreads();

    const int ph = lane >> 3, pw = lane & 7;
    const int i0 = ph * 32 + pw * 2;
    float x8 = fmaxf(fmaxf(xbuf[wv][i0], xbuf[wv][i0 + 1]),
                     fmaxf(xbuf[wv][i0 + 16], xbuf[wv][i0 + 17]));

    float myT = 0.f, myW = 0.f;
    #pragma unroll
    for (int k = 0; k < 25; ++k) {
        const int dy = k / 5 - 2, dx = k % 5 - 2;
        const bool valid = (ph + dy >= 0) && (ph + dy < 8) && (pw + dx >= 0) && (pw + dx < 8);
        float nb = __shfl(x8, (lane + dy * 8 + dx) & 63);
        nb = valid ? nb : 0.f;
        float tS = fast_tanh125(nb - x8);
        float wS = nb;
        #pragma unroll
        for (int off = 1; off < 64; off <<= 1) {
            tS += __shfl_xor(tS, off);
            wS += __shfl_xor(wS, off);
        }
        if (lane == k) { myT = tS; myW = wS; }
    }

    const int mt = b >> 4;
    if (lane < 25) {
        const int k = lane;
        const int la = (k >> 3) * 16 + (b & 15);
        const int e = k & 7;
        const int ccW = ch * 2, ccT = ch * 2 + 1;
        An[((size_t)(ccW * 4 + mt) * 64 + la) * 8 + e] = (__bf16)(myW * 0.015625f);
        An[((size_t)(ccT * 4 + mt) * 64 + la) * 8 + e] = (__bf16)(myT * 0.015625f);
    } else if (lane < 32) {
        // zero-fill padding slots (k=25..31) for determinism (ws is poisoned, not zeroed)
        const int la = 3 * 16 + (b & 15);
        const int e = lane & 7;
        const int ccW = ch * 2, ccT = ch * 2 + 1;
        An[((size_t)(ccW * 4 + mt) * 64 + la) * 8 + e] = (__bf16)0.f;
        An[((size_t)(ccT * 4 + mt) * 64 + la) * 8 + e] = (__bf16)0.f;
    }
}

// ---- tiny GEMM: feat-partials [96][192][64] = An[64 x 12288] * Bp3[12288 x 192]
__global__ __launch_bounds__(512) void gemm3p(
    const __bf16* __restrict__ An, const __bf16* __restrict__ Bp,
    float* __restrict__ part)
{
    const int ks = blockIdx.x;          // 96 blocks, 4 cc each
    const int tid = threadIdx.x;
    const int wv = tid >> 6, lane = tid & 63;
    const int mt = wv & 3, nh = wv >> 2;

    f32x4 acc[6];
    #pragma unroll
    for (int j = 0; j < 6; ++j) acc[j] = (f32x4){0.f, 0.f, 0.f, 0.f};

    for (int i = 0; i < 4; ++i) {
        const int cc = ks * 4 + i;
        bf16_8 a = *(const bf16_8*)(An + ((size_t)(cc * 4 + mt) * 64 + lane) * 8);
        #pragma unroll
        for (int j = 0; j < 6; ++j) {
            bf16_8 bw = *(const bf16_8*)(Bp + ((size_t)(cc * NF + nh * 6 + j) * 64 + lane) * 8);
            acc[j] = __builtin_amdgcn_mfma_f32_16x16x32_bf16(a, bw, acc[j], 0, 0, 0);
        }
    }
    #pragma unroll
    for (int j = 0; j < 6; ++j) {
        int n = (nh * 6 + j) * 16 + (lane & 15);
        *(f32x4*)(part + ((size_t)ks * COUT + n) * 64 + mt * 16 + (lane >> 4) * 4) = acc[j];
    }
}

// ---- logits: feat = sum of 96 partials + m3_b; logits = feat @ fc_w^T + fc_b
__global__ __launch_bounds__(256) void logitsk(
    const float* __restrict__ part, const float* __restrict__ m3_b,
    const float* __restrict__ fc_w, const float* __restrict__ fc_b,
    float* __restrict__ logits)
{
    __shared__ float feat[COUT];
    const int b = blockIdx.x;
    const int t = threadIdx.x;
    if (t < COUT) {
        float s = 0.f;
        for (int ks = 0; ks < 96; ++ks) s += part[((size_t)ks * COUT + t) * 64 + b];
        feat[t] = s + m3_b[t];
    }
    __syncthreads();
    if (t < 10) {
        float s = fc_b[t];
        #pragma unroll 8
        for (int c = 0; c < COUT; ++c) s = fmaf(fc_w[t * COUT + c], feat[c], s);
        logits[(size_t)b * 10 + t] = s;
    }
}

extern "C" void kernel_launch(void* const* d_in, const int* in_sizes, int n_in,
                              void* d_out, int out_size, void* d_ws, size_t ws_size,
                              hipStream_t stream) {
    const float* x    = (const float*)d_in[0];
    const float* m1_w = (const float*)d_in[1];
    const float* m1_b = (const float*)d_in[2];
    const float* w1_w = (const float*)d_in[3];
    const float* m2_w = (const float*)d_in[4];
    const float* m2_b = (const float*)d_in[5];
    const float* w2_w = (const float*)d_in[6];
    const float* m3_w = (const float*)d_in[7];
    const float* m3_b = (const float*)d_in[8];
    const float* w3_w = (const float*)d_in[9];
    const float* fc_w = (const float*)d_in[10];
    const float* fc_b = (const float*)d_in[11];

    float* out = (float*)d_out;
    float* ws  = (float*)d_ws;

    // d_out: [logits(640) | x00(3145728) | x01(3145728)]
    float* logits = out;
    float* x00 = out + 640;
    float* x01 = out + 640 + 3145728;

    // ws (float units):
    __bf16* Bp1  = (__bf16*)(ws);                //    36,864 bf16 (18,432 f)
    __bf16* Bp2  = (__bf16*)(ws + 18432);        // 2,359,296 bf16 (1,179,648 f)
    __bf16* Bp3  = (__bf16*)(ws + 1198080);      // 2,359,296 bf16 (1,179,648 f)
    __bf16* An   = (__bf16*)(ws + 2377728);      //   786,432 bf16 (393,216 f)
    float*  part2 = ws + 2770944;                // 9,437,184 f32 (ks=1..3 partials)
    float*  part3 = ws + 2770944;                // 1,179,648 f32 (ALIAS: written after part2's last read)
                                                 // total 12,208,128 f = 48.8 MB

    prep_w<3>  <<<(3   * 2 * NF * 64 + 255) / 256, 256, 0, stream>>>(m1_w, w1_w, Bp1);
    prep_w<192><<<(192 * 2 * NF * 64 + 255) / 256, 256, 0, stream>>>(m2_w, w2_w, Bp2);
    prep_w<192><<<(192 * 2 * NF * 64 + 255) / 256, 256, 0, stream>>>(m3_w, w3_w, Bp3);

    inrf1_mfma<<<64 * 16, 256, 0, stream>>>(x, Bp1, m1_b, x00);
    inrf2_mfma<<<64 * 4, 256, 0, stream>>>(x00, Bp2, x01, part2);
    finish2<<<64 * 24, 512, 0, stream>>>(x01, part2, m2_b, An);
    gemm3p<<<96, 512, 0, stream>>>(An, Bp3, part3);
    logitsk<<<64, 256, 0, stream>>>(part3, m3_b, fc_w, fc_b, logits);
}